// Round 8
// baseline (405.679 us; speedup 1.0000x reference)
//
#include <hip/hip_runtime.h>
#include <hip/hip_bf16.h>

#define B_ 8
#define L_ 1024
#define H_ 8
#define E_ 64
// p = 2^(score * 0.125 * log2(e))
#define CL2E 0.18033688f

typedef __attribute__((ext_vector_type(8))) short bf8v;
typedef __attribute__((ext_vector_type(4))) float f32x4;

__device__ __forceinline__ short f2bf(float x) {
    union { float f; unsigned u; } c; c.f = x;
    const unsigned r = (c.u + 0x7fffu + ((c.u >> 16) & 1u)) >> 16;
    return (short)r;
}

// ---------------------------------------------------------------------------
// prep: K -> bf16 [bh][s][e]  +  V -> bf16 transposed [bh][d][s].
// 1024 blocks x 256 thr; one (bh, 64-row) tile each.
// ---------------------------------------------------------------------------
__global__ __launch_bounds__(256) void prep_kernel(const float* __restrict__ K,
                                                   const float* __restrict__ V,
                                                   short* __restrict__ Kb,
                                                   short* __restrict__ VT) {
    const int bx = blockIdx.x;
    const int bh = bx >> 4; const int l0 = (bx & 15) << 6;
    const int b = bh >> 3, h = bh & 7;
    const int t = threadIdx.x;
    __shared__ float lds[64][65];

    const int r = t >> 2, cq = t & 3;
    // V rows -> LDS (f32)
    {
        const float* vsrc = V + ((size_t)((b * 1024 + l0 + r) * 8) + h) * 64 + (cq << 4);
#pragma unroll
        for (int j = 0; j < 4; ++j) {
            const float4 v = *(const float4*)(vsrc + (j << 2));
            const int d = (cq << 4) + (j << 2);
            lds[r][d] = v.x; lds[r][d + 1] = v.y; lds[r][d + 2] = v.z; lds[r][d + 3] = v.w;
        }
    }
    // K rows -> bf16 direct (same layout, dtype convert + head gather)
    {
        const float* ksrc = K + ((size_t)((b * 1024 + l0 + r) * 8) + h) * 64 + (cq << 4);
        short tk[16] __attribute__((aligned(16)));
#pragma unroll
        for (int j = 0; j < 4; ++j) {
            const float4 v = *(const float4*)(ksrc + (j << 2));
            tk[(j << 2) + 0] = f2bf(v.x); tk[(j << 2) + 1] = f2bf(v.y);
            tk[(j << 2) + 2] = f2bf(v.z); tk[(j << 2) + 3] = f2bf(v.w);
        }
        short* kdst = Kb + ((size_t)bh << 16) + (l0 + r) * 64 + (cq << 4);
        *(bf8v*)kdst = *(bf8v*)tk;
        *(bf8v*)(kdst + 8) = *(bf8v*)(tk + 8);
    }
    __syncthreads();
    // V^T out (bf16)
    {
        const int d = t >> 2, lq = t & 3;
        short tmp[16] __attribute__((aligned(16)));
#pragma unroll
        for (int k = 0; k < 16; ++k) tmp[k] = f2bf(lds[(lq << 4) + k][d]);
        short* dst = VT + ((size_t)bh << 16) + d * 1024 + l0 + (lq << 4);
        *(bf8v*)dst = *(bf8v*)tmp;
        *(bf8v*)(dst + 8) = *(bf8v*)(tmp + 8);
    }
}

// ---------------------------------------------------------------------------
// prior: 2048 blocks (b, 4-row group) x 256 thr; all-register, native rcp/exp2.
// ---------------------------------------------------------------------------
__global__ __launch_bounds__(256) void prior_kernel(const float* __restrict__ sigma,
                                                    float* __restrict__ outP) {
    const int bx = blockIdx.x;
    const int b  = bx >> 8;
    const int i0 = (bx & 255) << 2;
    const int t  = threadIdx.x;
    const int s0 = t << 2;

    __shared__ float wred[4][4];
    __shared__ float sinv[4];

    const float* sb = sigma + (size_t)b * H_ * L_;
    float wv[8][4];
#pragma unroll
    for (int h = 0; h < 8; ++h) {
        const float4 sg = *(const float4*)(sb + h * L_ + s0);
        wv[h][0] = -1.4426950408889634f * __builtin_amdgcn_rcpf(sg.x);
        wv[h][1] = -1.4426950408889634f * __builtin_amdgcn_rcpf(sg.y);
        wv[h][2] = -1.4426950408889634f * __builtin_amdgcn_rcpf(sg.z);
        wv[h][3] = -1.4426950408889634f * __builtin_amdgcn_rcpf(sg.w);
    }
    float acc[4][4];
#pragma unroll
    for (int row = 0; row < 4; ++row)
#pragma unroll
        for (int j = 0; j < 4; ++j) acc[row][j] = 0.f;
#pragma unroll
    for (int h = 0; h < 8; ++h)
#pragma unroll
        for (int row = 0; row < 4; ++row)
#pragma unroll
            for (int j = 0; j < 4; ++j) {
                int di = (i0 + row) - (s0 + j);
                const float dist = (float)(di < 0 ? -di : di);
                acc[row][j] += __builtin_amdgcn_exp2f(dist * wv[h][j]);
            }
    float tsum[4];
#pragma unroll
    for (int row = 0; row < 4; ++row) {
        float v = acc[row][0] + acc[row][1] + acc[row][2] + acc[row][3];
#pragma unroll
        for (int off = 1; off < 64; off <<= 1) v += __shfl_xor(v, off);
        tsum[row] = v;
    }
    if ((t & 63) == 0) {
#pragma unroll
        for (int row = 0; row < 4; ++row) wred[t >> 6][row] = tsum[row];
    }
    __syncthreads();
    if (t < 4) sinv[t] = 1.f / (wred[0][t] + wred[1][t] + wred[2][t] + wred[3][t]);
    __syncthreads();
#pragma unroll
    for (int row = 0; row < 4; ++row) {
        const float iv = sinv[row];
        float4 o;
        o.x = acc[row][0] * iv; o.y = acc[row][1] * iv;
        o.z = acc[row][2] * iv; o.w = acc[row][3] * iv;
        *(float4*)(outP + (size_t)(b * L_ + i0 + row) * L_ + s0) = o;
    }
}

// ---------------------------------------------------------------------------
// MFMA attention: 1024 blocks = (qtile 16, heavy first) x (bh 64); 4 waves.
// Double-buffered prefetch staging, 1 barrier/chunk. Pass A ascending chunks
// (QK+exp -> row sums); Pass B descending (reuses last staged K chunk):
// recompute QK, nt-write normalized P to outS, P->bf16 via swizzled LDS,
// PV mfma accumulate, write outV.
// ---------------------------------------------------------------------------
__global__ __launch_bounds__(256, 4) void attn_kernel(const float* __restrict__ Q,
                                                      const short* __restrict__ Kbf,
                                                      const short* __restrict__ VTbf,
                                                      float* __restrict__ outV,
                                                      float* __restrict__ outS) {
    const int bx = blockIdx.x;
    const int qt = 15 - (bx >> 6);          // heavy tiles dispatch first
    const int bh = bx & 63;
    const int b = bh >> 3, h = bh & 7;
    const int q0 = qt << 6;
    const int t = threadIdx.x;
    const int lane = t & 63, w = t >> 6;
    const int l15 = lane & 15, l4 = lane >> 4;
    const int nch = qt + 1;

    // [buf][ K tile 8KB | V tile 8KB ] x2  +  P 8KB  = 40960 B (4 blocks/CU)
    __shared__ __align__(16) short stage[2][8192];
    __shared__ __align__(16) short Plds[4096];

    const short* Kb = Kbf + ((size_t)bh << 16);
    const short* Vb = VTbf + ((size_t)bh << 16);

    // staging lane geometry: 8 rows x 8 slots of 16B per wave-instruction
    const int srow = lane >> 3;
    const int sslot = lane & 7;
    const int pslot = sslot ^ srow;              // XOR swizzle (row&7)
    const int krow0 = 16 * w + srow;             // rows r and r+8
    const int stb0 = krow0 * 128 + (pslot << 4);
    const int stb1 = stb0 + 8 * 128;
    const short* kbase = Kb + krow0 * 64 + sslot * 8;     // +c*4096; row+8 -> +512
    const short* vbase = Vb + krow0 * 1024 + sslot * 8;   // +c*64;   row+8 -> +8192

    // Q A-fragments: row = lane&15, k = (lane>>4)*8 + j
    bf8v aq0, aq1;
    {
        const float* Qrow = Q + ((size_t)((b * 1024 + q0 + 16 * w + l15) * 8) + h) * 64 + l4 * 8;
#pragma unroll
        for (int j = 0; j < 8; ++j) aq0[j] = f2bf(Qrow[j]);
#pragma unroll
        for (int j = 0; j < 8; ++j) aq1[j] = f2bf(Qrow[32 + j]);
    }

    float* outSb = outS + ((size_t)bh << 20) + (size_t)q0 * 1024;

    bf8v kA, kB, vA, vB;

    // ---------------- Pass A prologue: chunk 0 + causal zero-fill ----------
    kA = *(const bf8v*)(kbase);
    kB = *(const bf8v*)(kbase + 512);
    {
        const int cend = nch << 6;
        const f32x4 z4 = {0.f, 0.f, 0.f, 0.f};
        for (int col = cend + (lane << 2); col < 1024; col += 256) {
            float* rp = outSb + (size_t)(16 * w) * 1024 + col;
#pragma unroll
            for (int rr = 0; rr < 16; ++rr)
                __builtin_nontemporal_store(z4, (f32x4*)(rp + (size_t)rr * 1024));
        }
    }
    {
        char* d0 = (char*)stage[0];
        *(bf8v*)(d0 + stb0) = kA;
        *(bf8v*)(d0 + stb1) = kB;
    }
    __syncthreads();

    // ---------------- Pass A: row sums (ascending chunks) ----------------
    float sum4[4] = {0.f, 0.f, 0.f, 0.f};
    for (int c = 0; c < nch; ++c) {
        if (c + 1 < nch) {
            kA = *(const bf8v*)(kbase + (size_t)(c + 1) * 4096);
            kB = *(const bf8v*)(kbase + (size_t)(c + 1) * 4096 + 512);
        }
        const char* kt = (const char*)stage[c & 1];
        const bool diag = (c == qt);
#pragma unroll
        for (int cb = 0; cb < 4; ++cb) {
            const int krow = (cb << 4) + l15;
            const char* kp = kt + krow * 128;
            const int sw = (krow & 7) << 4;
            const bf8v b0 = *(const bf8v*)(kp + ((l4 << 4) ^ sw));
            const bf8v b1 = *(const bf8v*)(kp + ((64 + (l4 << 4)) ^ sw));
            f32x4 acc = {0.f, 0.f, 0.f, 0.f};
            acc = __builtin_amdgcn_mfma_f32_16x16x32_bf16(aq0, b0, acc, 0, 0, 0);
            acc = __builtin_amdgcn_mfma_f32_16x16x32_bf16(aq1, b1, acc, 0, 0, 0);
#pragma unroll
            for (int r = 0; r < 4; ++r) {
                float e = __builtin_amdgcn_exp2f(acc[r] * CL2E);
                if (diag && ((cb << 4) + l15 > 16 * w + (l4 << 2) + r)) e = 0.f;
                sum4[r] += e;
            }
        }
        if (c + 1 < nch) {
            char* dn = (char*)stage[(c + 1) & 1];
            *(bf8v*)(dn + stb0) = kA;
            *(bf8v*)(dn + stb1) = kB;
        }
        __syncthreads();
    }

    // ---------------- reduce row sums (16-lane groups) + stage V(last) -----
    vA = *(const bf8v*)(vbase + (nch - 1) * 64);
    vB = *(const bf8v*)(vbase + (nch - 1) * 64 + 8192);
#pragma unroll
    for (int r = 0; r < 4; ++r) {
        float v = sum4[r];
        v += __shfl_xor(v, 1); v += __shfl_xor(v, 2);
        v += __shfl_xor(v, 4); v += __shfl_xor(v, 8);
        sum4[r] = v;
    }
    float inv4[4];
#pragma unroll
    for (int r = 0; r < 4; ++r) inv4[r] = __builtin_amdgcn_rcpf(sum4[r]);
    {
        char* sv = (char*)stage[(nch - 1) & 1] + 8192;
        *(bf8v*)(sv + stb0) = vA;
        *(bf8v*)(sv + stb1) = vB;
    }
    __syncthreads();

    // ---------------- Pass B: descending chunks (K(last) already in LDS) ---
    f32x4 oacc[4];
#pragma unroll
    for (int db = 0; db < 4; ++db) oacc[db] = (f32x4){0.f, 0.f, 0.f, 0.f};

    short* Pw = Plds + (w << 10);
    float* sbase = outSb + (size_t)(16 * w + (l4 << 2)) * 1024 + l15;

    for (int c = nch - 1; c >= 0; --c) {
        if (c > 0) {
            kA = *(const bf8v*)(kbase + (size_t)(c - 1) * 4096);
            kB = *(const bf8v*)(kbase + (size_t)(c - 1) * 4096 + 512);
            vA = *(const bf8v*)(vbase + (c - 1) * 64);
            vB = *(const bf8v*)(vbase + (c - 1) * 64 + 8192);
        }
        const int s0 = c << 6;
        const char* kt = (const char*)stage[c & 1];
        const char* vt = kt + 8192;
        const bool diag = (c == qt);
#pragma unroll
        for (int cb = 0; cb < 4; ++cb) {
            const int krow = (cb << 4) + l15;
            const char* kp = kt + krow * 128;
            const int sw = (krow & 7) << 4;
            const bf8v b0 = *(const bf8v*)(kp + ((l4 << 4) ^ sw));
            const bf8v b1 = *(const bf8v*)(kp + ((64 + (l4 << 4)) ^ sw));
            f32x4 acc = {0.f, 0.f, 0.f, 0.f};
            acc = __builtin_amdgcn_mfma_f32_16x16x32_bf16(aq0, b0, acc, 0, 0, 0);
            acc = __builtin_amdgcn_mfma_f32_16x16x32_bf16(aq1, b1, acc, 0, 0, 0);
#pragma unroll
            for (int r = 0; r < 4; ++r) {
                float e = __builtin_amdgcn_exp2f(acc[r] * CL2E);
                if (diag && ((cb << 4) + l15 > 16 * w + (l4 << 2) + r)) e = 0.f;
                const float pv = e * inv4[r];
                __builtin_nontemporal_store(pv, sbase + (size_t)r * 1024 + s0 + (cb << 4));
                const int row = (l4 << 2) + r;
                const int byte = row * 128 +
                                 ((((cb << 1) + (l15 >> 3)) ^ (row & 7)) << 4) +
                                 ((l15 & 7) << 1);
                *(short*)((char*)Pw + byte) = f2bf(pv);
            }
        }
        // PV: A = P (row=q local=lane&15), B = V^T rows
        const int swp = (l15 & 7) << 4;
        const bf8v p0 = *(const bf8v*)((char*)Pw + l15 * 128 + ((l4 << 4) ^ swp));
        const bf8v p1 = *(const bf8v*)((char*)Pw + l15 * 128 + (((4 + l4) << 4) ^ swp));
#pragma unroll
        for (int db = 0; db < 4; ++db) {
            const int vrow = (db << 4) + l15;
            const char* vp = vt + vrow * 128;
            const int swv = (vrow & 7) << 4;
            const bf8v v0 = *(const bf8v*)(vp + ((l4 << 4) ^ swv));
            const bf8v v1 = *(const bf8v*)(vp + (((4 + l4) << 4) ^ swv));
            oacc[db] = __builtin_amdgcn_mfma_f32_16x16x32_bf16(p0, v0, oacc[db], 0, 0, 0);
            oacc[db] = __builtin_amdgcn_mfma_f32_16x16x32_bf16(p1, v1, oacc[db], 0, 0, 0);
        }
        if (c > 0) {
            char* dn = (char*)stage[(c - 1) & 1];
            *(bf8v*)(dn + stb0) = kA;
            *(bf8v*)(dn + stb1) = kB;
            *(bf8v*)(dn + 8192 + stb0) = vA;
            *(bf8v*)(dn + 8192 + stb1) = vB;
        }
        __syncthreads();
    }

#pragma unroll
    for (int db = 0; db < 4; ++db)
#pragma unroll
        for (int r = 0; r < 4; ++r)
            outV[((size_t)((b * 1024 + q0 + 16 * w + (l4 << 2) + r) * 8) + h) * 64 +
                 (db << 4) + l15] = oacc[db][r];
}

extern "C" void kernel_launch(void* const* d_in, const int* in_sizes, int n_in,
                              void* d_out, int out_size, void* d_ws, size_t ws_size,
                              hipStream_t stream) {
    const float* Q     = (const float*)d_in[0];
    const float* K     = (const float*)d_in[1];
    const float* V     = (const float*)d_in[2];
    const float* sigma = (const float*)d_in[3];

    float* out  = (float*)d_out;
    float* outV = out;                                    // (B,L,H,D)   4,194,304
    float* outS = out + (size_t)B_ * L_ * H_ * E_;        // (B,H,L,S)  67,108,864
    float* outP = outS + (size_t)B_ * H_ * L_ * L_;       // (B,L,S)     8,388,608

    short* Kbf = (short*)outP;                            // 8.39 MB staging
    short* VTb = Kbf + ((size_t)64 << 16);                // 8.39 MB staging

    prep_kernel<<<dim3(1024), dim3(256), 0, stream>>>(K, V, Kbf, VTb);
    attn_kernel<<<dim3(1024), dim3(256), 0, stream>>>(Q, Kbf, VTb, outV, outS);
    prior_kernel<<<dim3(B_ * (L_ / 4)), dim3(256), 0, stream>>>(sigma, outP);
}